// Round 15
// baseline (98.152 us; speedup 1.0000x reference)
//
#include <hip/hip_runtime.h>
#include <hip/hip_bf16.h>

// Problem constants: B=4, S=2048, D=512, H=8, DK=64
// ws layout (bytes):
//   Xb    @ 0        : 8192*512 bf16        = 8388608
//   Wqkv  @ 8388608  : 1536*512 bf16        = 1572864   (BT: row n = which*512+h*64+dk, col k=d)
//   WoT   @ 9961472  : 512*512 bf16         = 524288    (row n=d, col k=h*64+dk  [permuted concat])
//   Qb    @ 10485760 : 8388608   ([bh][s][dk], PRE-SCALED by log2(e)/8)
//   Kb    @ 18874368 : 8388608   ([bh][s][dk])
//   VTb   @ 27262976 : 8388608   ([bh][dk][s])
//   Oc    @ 35651584 : 8388608   ([b][s][h*64+dk])
// total 44040192 bytes

typedef __bf16 bf16;
typedef __bf16 bf16x8 __attribute__((ext_vector_type(8)));
typedef __bf16 bf16x4 __attribute__((ext_vector_type(4)));
typedef __bf16 bf16x2 __attribute__((ext_vector_type(2)));
typedef float  f32x4  __attribute__((ext_vector_type(4)));
typedef float  f32x16 __attribute__((ext_vector_type(16)));
typedef unsigned int u32;
typedef u32 u32x4 __attribute__((ext_vector_type(4)));

#define AS1 __attribute__((address_space(1)))
#define AS3 __attribute__((address_space(3)))

__device__ __forceinline__ void async_lds16(const void* gsrc, void* ldst) {
  __builtin_amdgcn_global_load_lds((AS1 const void*)gsrc, (AS3 void*)ldst, 16, 0, 0);
}

// single-instruction exp2 (args bounded above by THR=8; very-negative -> 0)
__device__ __forceinline__ float fexp2(float x) {
  float r;
  asm("v_exp_f32 %0, %1" : "=v"(r) : "v"(x));
  return r;
}

// ---------------- fused converter: X->bf16, Wq/Wk/Wv->BT, Wo->WoT ----------------

__global__ __launch_bounds__(256) void k_cvt_all(const float4* __restrict__ X4,
                                                 const float* __restrict__ Wq,
                                                 const float* __restrict__ Wk,
                                                 const float* __restrict__ Wv,
                                                 const float* __restrict__ Wo,
                                                 bf16x4* __restrict__ Xb4,
                                                 bf16* __restrict__ BT,
                                                 bf16* __restrict__ WoT) {
  int t = blockIdx.x * 256 + threadIdx.x;       // < 2097152
  if (t < 1048576) {
    float4 v = X4[t];
    bf16x4 o = { (bf16)v.x, (bf16)v.y, (bf16)v.z, (bf16)v.w };
    Xb4[t] = o;
  } else {
    int u = t - 1048576;                        // < 1048576
    if (u < 786432) {
      int n = u >> 9, d = u & 511;
      int which = n >> 9, h = (n >> 6) & 7, dk = n & 63;
      const float* W = (which == 0) ? Wq : ((which == 1) ? Wk : Wv);
      BT[u] = (bf16)W[((h << 9) + d) * 64 + dk];
    } else {
      int i2 = u - 786432;                      // < 262144
      int d = i2 >> 9, c = i2 & 511;
      int h = c >> 6, dk = c & 63;
      WoT[i2] = (bf16)Wo[(((dk << 3) + h) << 9) + d];
    }
  }
}

// ---------------- GEMM mainloop: 128x128 tile, BK=32, 4 waves ----------------
// T3+T4: TRIPLE-buffered LDS with COUNTED vmcnt (m218: counted-vs-drain0 was
// the +38-73% lever). Per thread, each stage = exactly 4 global_load_lds, so
// vmcnt(4) before the barrier guarantees tile-t's loads landed while leaving
// tile-(t+1)'s in flight. stage(t+2) issued AFTER the barrier overwrites
// buf(t-1): all waves past barrier t have consumed their t-1 ds_reads
// (lgkmcnt precedes MFMA use), so no WAR hazard.

__device__ __forceinline__ void gemm_tile(const bf16* __restrict__ A,
                                          const bf16* __restrict__ BT,
                                          int K, int m0, int n0,
                                          char* sm, f32x4 acc[4][4]) {
  const int tid = threadIdx.x;
  const int lane = tid & 63, w = tid >> 6;
  const int wm = w >> 1, wn = w & 1;
  const int lr = lane & 15, lg = lane >> 4;
#define GSTAGE(bi, k0) do {                                                        \
    char* base_ = sm + (bi) * 16384;                                               \
    _Pragma("unroll")                                                              \
    for (int i_ = 0; i_ < 2; ++i_) {                                               \
      int off_ = i_ * 256 + tid;                                                   \
      int row_ = off_ >> 2, cb_ = (off_ & 3) << 4;                                 \
      async_lds16((const char*)(A  + (m0 + row_) * K + (k0)) + cb_,                \
                  base_ + off_ * 16);                                              \
      async_lds16((const char*)(BT + (n0 + row_) * K + (k0)) + cb_,                \
                  base_ + 8192 + off_ * 16);                                       \
    }                                                                              \
  } while (0)
  const int NT = K >> 5;
  GSTAGE(0, 0);
  if (NT > 1) GSTAGE(1, 32);
  int cur = 0;
  for (int t = 0; t < NT; ++t) {
    if (t + 1 < NT) asm volatile("s_waitcnt vmcnt(4)" ::: "memory");
    else            asm volatile("s_waitcnt vmcnt(0)" ::: "memory");
    __builtin_amdgcn_s_barrier();
    if (t + 2 < NT) {
      int nb = cur + 2; if (nb >= 3) nb -= 3;
      GSTAGE(nb, (t + 2) << 5);
    }
    char* cb = sm + cur * 16384;
    bf16x8 af[4], bfr[4];
    #pragma unroll
    for (int u = 0; u < 4; ++u) {
      af[u]  = *(const bf16x8*)(cb +        ((wm * 64 + u * 16 + lr) * 32 + 8 * lg) * 2);
      bfr[u] = *(const bf16x8*)(cb + 8192 + ((wn * 64 + u * 16 + lr) * 32 + 8 * lg) * 2);
    }
    __builtin_amdgcn_s_setprio(1);
    #pragma unroll
    for (int am = 0; am < 4; ++am)
      #pragma unroll
      for (int bn = 0; bn < 4; ++bn)
        acc[am][bn] = __builtin_amdgcn_mfma_f32_16x16x32_bf16(af[am], bfr[bn], acc[am][bn], 0, 0, 0);
    __builtin_amdgcn_s_setprio(0);
    cur = (cur == 2) ? 0 : cur + 1;
  }
#undef GSTAGE
}

__global__ __launch_bounds__(256) void k_gemm_qkv(const bf16* __restrict__ A,
                                                  const bf16* __restrict__ BT,
                                                  bf16* __restrict__ Qb,
                                                  bf16* __restrict__ Kb,
                                                  bf16* __restrict__ VTb) {
  __shared__ char sm[49152];
  const int m0 = blockIdx.y * 128, n0 = blockIdx.x * 128;
  f32x4 acc[4][4];
  #pragma unroll
  for (int a = 0; a < 4; ++a)
    #pragma unroll
    for (int b = 0; b < 4; ++b) { f32x4 z = {0.f,0.f,0.f,0.f}; acc[a][b] = z; }
  gemm_tile(A, BT, 512, m0, n0, sm, acc);
  const int lane = threadIdx.x & 63, w = threadIdx.x >> 6;
  const int wm = w >> 1, wn = w & 1, lr = lane & 15, lg = lane >> 4;
  const float qsc = 0.1803368801f;  // log2(e)/sqrt(64), folded into Q
  #pragma unroll
  for (int am = 0; am < 4; ++am)
    #pragma unroll
    for (int bn = 0; bn < 4; ++bn)
      #pragma unroll
      for (int r = 0; r < 4; ++r) {
        int m = m0 + wm * 64 + am * 16 + 4 * lg + r;
        int n = n0 + wn * 64 + bn * 16 + lr;
        int b = m >> 11, s = m & 2047;
        int which = n >> 9, h = (n >> 6) & 7, dk = n & 63;
        int bh = (b << 3) + h;
        float x = acc[am][bn][r];
        if (which == 0)      Qb[((bh << 11) + s) * 64 + dk] = (bf16)(x * qsc);
        else if (which == 1) Kb[((bh << 11) + s) * 64 + dk] = (bf16)x;
        else                 VTb[((bh << 6) + dk) * 2048 + s] = (bf16)x;
      }
}

// output GEMM: 128(M)x64(N) tile, grid 512 = 2 blocks/CU; counted-vmcnt
// triple buffer (3 loads/thread/tile -> vmcnt(3)).
__global__ __launch_bounds__(256) void k_gemm_out(const bf16* __restrict__ A,
                                                  const bf16* __restrict__ BT,
                                                  float* __restrict__ C) {
  __shared__ char sm[36864];
  const int m0 = blockIdx.y * 128, n0 = blockIdx.x * 64;
  const int tid = threadIdx.x;
  const int lane = tid & 63, w = tid >> 6;
  const int wm = w >> 1, wn = w & 1;
  const int lr = lane & 15, lg = lane >> 4;
  f32x4 acc[4][2];
  #pragma unroll
  for (int a = 0; a < 4; ++a)
    #pragma unroll
    for (int b = 0; b < 2; ++b) { f32x4 z = {0.f,0.f,0.f,0.f}; acc[a][b] = z; }
#define GSTAGE2(bi, k0) do {                                                       \
    char* base_ = sm + (bi) * 12288;                                               \
    _Pragma("unroll")                                                              \
    for (int i_ = 0; i_ < 2; ++i_) {                                               \
      int off_ = i_ * 256 + tid;                                                   \
      int row_ = off_ >> 2, cb_ = (off_ & 3) << 4;                                 \
      async_lds16((const char*)(A + (m0 + row_) * 512 + (k0)) + cb_,               \
                  base_ + off_ * 16);                                              \
    }                                                                              \
    {                                                                              \
      int off_ = tid;                                                              \
      int row_ = off_ >> 2, cb_ = (off_ & 3) << 4;                                 \
      async_lds16((const char*)(BT + (n0 + row_) * 512 + (k0)) + cb_,              \
                  base_ + 8192 + off_ * 16);                                       \
    }                                                                              \
  } while (0)
  GSTAGE2(0, 0);
  GSTAGE2(1, 32);
  int cur = 0;
  for (int t = 0; t < 16; ++t) {
    if (t + 1 < 16) asm volatile("s_waitcnt vmcnt(3)" ::: "memory");
    else            asm volatile("s_waitcnt vmcnt(0)" ::: "memory");
    __builtin_amdgcn_s_barrier();
    if (t + 2 < 16) {
      int nb = cur + 2; if (nb >= 3) nb -= 3;
      GSTAGE2(nb, (t + 2) << 5);
    }
    char* cb = sm + cur * 12288;
    bf16x8 af[4], bfr[2];
    #pragma unroll
    for (int u = 0; u < 4; ++u)
      af[u] = *(const bf16x8*)(cb + ((wm * 64 + u * 16 + lr) * 32 + 8 * lg) * 2);
    #pragma unroll
    for (int v = 0; v < 2; ++v)
      bfr[v] = *(const bf16x8*)(cb + 8192 + ((wn * 32 + v * 16 + lr) * 32 + 8 * lg) * 2);
    __builtin_amdgcn_s_setprio(1);
    #pragma unroll
    for (int am = 0; am < 4; ++am)
      #pragma unroll
      for (int bn = 0; bn < 2; ++bn)
        acc[am][bn] = __builtin_amdgcn_mfma_f32_16x16x32_bf16(af[am], bfr[bn], acc[am][bn], 0, 0, 0);
    __builtin_amdgcn_s_setprio(0);
    cur = (cur == 2) ? 0 : cur + 1;
  }
#undef GSTAGE2
  #pragma unroll
  for (int am = 0; am < 4; ++am)
    #pragma unroll
    for (int bn = 0; bn < 2; ++bn)
      #pragma unroll
      for (int r = 0; r < 4; ++r) {
        int m = m0 + wm * 64 + am * 16 + 4 * lg + r;
        int n = n0 + wn * 32 + bn * 16 + lr;
        C[(m << 9) + n] = acc[am][bn][r];
      }
}

// ---------------- causal flash attention: q-split, LDS-staged K/V, counted vmcnt ----------------
// r11 body (proven 42.7us) with the T4 pipeline: 3 x 16KB buffers, per-thread
// 4 gload_lds per stage -> vmcnt(4)+raw-barrier per tile, stage(t+2) after the
// barrier. The full vmcnt(0) drain (per-tile L2/L3 stage latency on the
// critical path) is gone; loads now have ~2 tiles of compute to land.
// Block = 4 waves x 32 DIFFERENT q-rows (128 rows) of one (b,h). KVBLK=64.
// Swizzle rule #21: linear LDS dest + source-XOR + read-XOR.
// Private per-wave online softmax (no cross-wave combine).

__device__ __forceinline__ void attn_stage(char* base, const bf16* Kh, const bf16* Vh,
                                           int tb, int tid) {
  #pragma unroll
  for (int k = 0; k < 2; ++k) {        // K slots 0..511
    int s = tid + (k << 8);
    int row = s >> 3, g = s & 7;
    async_lds16((const void*)(Kh + ((tb + row) << 6) + ((g ^ (row & 7)) << 3)),
                base + s * 16);
  }
  #pragma unroll
  for (int k = 0; k < 2; ++k) {        // V slots 0..511 (dv-major)
    int s = tid + (k << 8);
    int row = s >> 3, g = s & 7;
    async_lds16((const void*)(Vh + (row << 11) + tb + ((g ^ (row & 7)) << 3)),
                base + 8192 + s * 16);
  }
}

__global__ __launch_bounds__(256, 2) void k_attn6(const bf16* __restrict__ Qb,
                                                  const bf16* __restrict__ Kb,
                                                  const bf16* __restrict__ VTb,
                                                  bf16* __restrict__ Oc) {
  __shared__ char sm[49152];
  const int tid = threadIdx.x, lane = tid & 63, wv = tid >> 6;
  const int l31 = lane & 31, hi = lane >> 5;
  const int bid = blockIdx.x;
  const int bh = bid & 31;
  const int qb = (bid < 256) ? (15 - (bid >> 5)) : ((bid - 256) >> 5);
  const int b = bh >> 3, h = bh & 7;
  const int q0 = qb << 7;
  const int wq0 = q0 + (wv << 5);                // this wave's first q-row
  const bf16* Qh = Qb  + ((size_t)bh << 17);
  const bf16* Kh = Kb  + ((size_t)bh << 17);
  const bf16* Vh = VTb + ((size_t)bh << 17);

  bf16x8 qf[4];
  #pragma unroll
  for (int kd = 0; kd < 4; ++kd)
    qf[kd] = *(const bf16x8*)(Qh + ((wq0 + l31) << 6) + kd * 16 + 8 * hi);

  f32x16 o0, o1;
  #pragma unroll
  for (int r = 0; r < 16; ++r) { o0[r] = 0.f; o1[r] = 0.f; }
  float m_run = -3e38f, lsum = 0.f;

  const int NT = (qb << 1) + 2;                  // tiles cover kv [0, q0+128)
  const int swz = l31 & 7;                       // row&7 for all this lane's reads

  attn_stage(sm, Kh, Vh, 0, tid);
  if (NT > 1) attn_stage(sm + 16384, Kh, Vh, 64, tid);
  int cur = 0;

  for (int t = 0; t < NT; ++t) {
    const int tb = t << 6;
    if (t + 1 < NT) asm volatile("s_waitcnt vmcnt(4)" ::: "memory");
    else            asm volatile("s_waitcnt vmcnt(0)" ::: "memory");
    __builtin_amdgcn_s_barrier();
    if (t + 2 < NT) {
      int nb = cur + 2; if (nb >= 3) nb -= 3;
      attn_stage(sm + nb * 16384, Kh, Vh, (t + 2) << 6, tid);
    }
    char* cb = sm + cur * 16384;
    cur = (cur == 2) ? 0 : cur + 1;
    if (tb > wq0 + 31) continue;                 // fully above diagonal for this wave

    // QK^T from K LDS: two 32-kv halves
    f32x16 sA, sB;
    #pragma unroll
    for (int r = 0; r < 16; ++r) { sA[r] = 0.f; sB[r] = 0.f; }
    {
      bf16x8 kf[4];
      #pragma unroll
      for (int kd = 0; kd < 4; ++kd)
        kf[kd] = *(const bf16x8*)(cb + l31 * 128 + ((((kd << 1) + hi) ^ swz) << 4));
      __builtin_amdgcn_s_setprio(1);
      #pragma unroll
      for (int kd = 0; kd < 4; ++kd)
        sA = __builtin_amdgcn_mfma_f32_32x32x16_bf16(kf[kd], qf[kd], sA, 0, 0, 0);
      __builtin_amdgcn_s_setprio(0);
      #pragma unroll
      for (int kd = 0; kd < 4; ++kd)
        kf[kd] = *(const bf16x8*)(cb + (32 + l31) * 128 + ((((kd << 1) + hi) ^ swz) << 4));
      __builtin_amdgcn_s_setprio(1);
      #pragma unroll
      for (int kd = 0; kd < 4; ++kd)
        sB = __builtin_amdgcn_mfma_f32_32x32x16_bf16(kf[kd], qf[kd], sB, 0, 0, 0);
      __builtin_amdgcn_s_setprio(0);
    }

    const int sg = wq0 + l31;
    // causal mask (only tiles overlapping the diagonal band)
    if (tb + 63 > wq0) {
      #pragma unroll
      for (int r = 0; r < 16; ++r) {
        int rk = tb + (r & 3) + 8 * (r >> 2) + 4 * hi;
        sA[r] = (rk > sg)      ? -1e30f : sA[r];
        sB[r] = (rk + 32 > sg) ? -1e30f : sB[r];
      }
    }
    // row max: tree + one cross-half exchange
    float tv[16];
    #pragma unroll
    for (int r = 0; r < 16; ++r) tv[r] = fmaxf(sA[r], sB[r]);
    float m0_ = fmaxf(tv[0], tv[1]),  m1_ = fmaxf(tv[2], tv[3]);
    float m2_ = fmaxf(tv[4], tv[5]),  m3_ = fmaxf(tv[6], tv[7]);
    float m4_ = fmaxf(tv[8], tv[9]),  m5_ = fmaxf(tv[10], tv[11]);
    float m6_ = fmaxf(tv[12], tv[13]), m7_ = fmaxf(tv[14], tv[15]);
    float tmax = fmaxf(fmaxf(fmaxf(m0_, m1_), fmaxf(m2_, m3_)),
                       fmaxf(fmaxf(m4_, m5_), fmaxf(m6_, m7_)));
    float tms = fmaxf(tmax, __shfl_xor(tmax, 32));
    // defer-max rescale (T13, THR=8 in exp2 domain)
    if (!__all(tms <= m_run + 8.f)) {
      float mn = fmaxf(m_run, tms);
      float fac = fexp2(m_run - mn);
      #pragma unroll
      for (int r = 0; r < 16; ++r) { o0[r] *= fac; o1[r] *= fac; }
      lsum *= fac;
      m_run = mn;
    }
    // P = exp2(s - m) in place
    #pragma unroll
    for (int r = 0; r < 16; ++r) sA[r] = fexp2(sA[r] - m_run);
    #pragma unroll
    for (int r = 0; r < 16; ++r) sB[r] = fexp2(sB[r] - m_run);
    // row sum
    float a0 = (sA[0]+sB[0]) + (sA[1]+sB[1]),   a1 = (sA[2]+sB[2]) + (sA[3]+sB[3]);
    float a2 = (sA[4]+sB[4]) + (sA[5]+sB[5]),   a3 = (sA[6]+sB[6]) + (sA[7]+sB[7]);
    float a4 = (sA[8]+sB[8]) + (sA[9]+sB[9]),   a5 = (sA[10]+sB[10]) + (sA[11]+sB[11]);
    float a6 = (sA[12]+sB[12]) + (sA[13]+sB[13]), a7 = (sA[14]+sB[14]) + (sA[15]+sB[15]);
    float rs = ((a0 + a1) + (a2 + a3)) + ((a4 + a5) + (a6 + a7));
    lsum += rs + __shfl_xor(rs, 32);

    // per 32-kv half: pack P, permlane -> B-frags; PV from V LDS
    #pragma unroll
    for (int j = 0; j < 2; ++j) {
      u32 pk_[8];
      #pragma unroll
      for (int i = 0; i < 8; ++i) {
        float plo = j ? sB[2 * i] : sA[2 * i];
        float phi = j ? sB[2 * i + 1] : sA[2 * i + 1];
        bf16x2 pr = { (bf16)plo, (bf16)phi };
        pk_[i] = __builtin_bit_cast(u32, pr);
      }
      asm volatile("v_permlane32_swap_b32 %0, %1" : "+v"(pk_[0]), "+v"(pk_[2]));
      asm volatile("v_permlane32_swap_b32 %0, %1" : "+v"(pk_[1]), "+v"(pk_[3]));
      asm volatile("v_permlane32_swap_b32 %0, %1" : "+v"(pk_[4]), "+v"(pk_[6]));
      asm volatile("v_permlane32_swap_b32 %0, %1" : "+v"(pk_[5]), "+v"(pk_[7]));
      u32x4 w0 = { pk_[0], pk_[1], pk_[2], pk_[3] };
      u32x4 w1 = { pk_[4], pk_[5], pk_[6], pk_[7] };
      bf16x8 pb0 = __builtin_bit_cast(bf16x8, w0);
      bf16x8 pb1 = __builtin_bit_cast(bf16x8, w1);
      // V^T A-frags from LDS: dv = dvt*32+l31, 16B-group gg = j*4 + ks*2 + hi
      const char* vb = cb + 8192;
      bf16x8 v00 = *(const bf16x8*)(vb + l31 * 128        + ((((j << 2) + hi) ^ swz) << 4));
      bf16x8 v01 = *(const bf16x8*)(vb + l31 * 128        + ((((j << 2) + 2 + hi) ^ swz) << 4));
      bf16x8 v10 = *(const bf16x8*)(vb + (32 + l31) * 128 + ((((j << 2) + hi) ^ swz) << 4));
      bf16x8 v11 = *(const bf16x8*)(vb + (32 + l31) * 128 + ((((j << 2) + 2 + hi) ^ swz) << 4));
      __builtin_amdgcn_s_setprio(1);
      o0 = __builtin_amdgcn_mfma_f32_32x32x16_bf16(v00, pb0, o0, 0, 0, 0);
      o0 = __builtin_amdgcn_mfma_f32_32x32x16_bf16(v01, pb1, o0, 0, 0, 0);
      o1 = __builtin_amdgcn_mfma_f32_32x32x16_bf16(v10, pb0, o1, 0, 0, 0);
      o1 = __builtin_amdgcn_mfma_f32_32x32x16_bf16(v11, pb1, o1, 0, 0, 0);
      __builtin_amdgcn_s_setprio(0);
    }
  }

  // epilogue: per-wave normalize and coalesced write (no cross-wave combine)
  float rn = 1.f / lsum;
  const int sg = wq0 + l31;
  bf16* Orow = Oc + (((size_t)((b << 11) + sg)) << 9) + (h << 6);
  #pragma unroll
  for (int g = 0; g < 4; ++g) {
    bf16x4 v0, v1;
    #pragma unroll
    for (int i = 0; i < 4; ++i) {
      v0[i] = (bf16)(o0[4 * g + i] * rn);
      v1[i] = (bf16)(o1[4 * g + i] * rn);
    }
    *(bf16x4*)(Orow + 4 * hi + 8 * g)      = v0;
    *(bf16x4*)(Orow + 32 + 4 * hi + 8 * g) = v1;
  }
}

// ---------------- launch ----------------

extern "C" void kernel_launch(void* const* d_in, const int* in_sizes, int n_in,
                              void* d_out, int out_size, void* d_ws, size_t ws_size,
                              hipStream_t stream) {
  (void)in_sizes; (void)n_in; (void)out_size; (void)ws_size;
  const float* X  = (const float*)d_in[0];
  const float* Wq = (const float*)d_in[1];
  const float* Wk = (const float*)d_in[2];
  const float* Wv = (const float*)d_in[3];
  const float* Wo = (const float*)d_in[4];
  float* out = (float*)d_out;
  char* ws = (char*)d_ws;
  bf16* Xb   = (bf16*)(ws);
  bf16* Wqkv = (bf16*)(ws + 8388608);
  bf16* WoT  = (bf16*)(ws + 9961472);
  bf16* Qb   = (bf16*)(ws + 10485760);
  bf16* Kb   = (bf16*)(ws + 18874368);
  bf16* VTb  = (bf16*)(ws + 27262976);
  bf16* Oc   = (bf16*)(ws + 35651584);

  k_cvt_all<<<8192, 256, 0, stream>>>((const float4*)X, Wq, Wk, Wv, Wo,
                                      (bf16x4*)Xb, Wqkv, WoT);
  k_gemm_qkv<<<dim3(12, 64), 256, 0, stream>>>(Xb, Wqkv, Qb, Kb, VTb);
  k_attn6<<<512, 256, 0, stream>>>(Qb, Kb, VTb, Oc);
  k_gemm_out<<<dim3(8, 64), 256, 0, stream>>>(Oc, WoT, out);
}

// Round 16
// 91.839 us; speedup vs baseline: 1.0687x; 1.0687x over previous
//
#include <hip/hip_runtime.h>
#include <hip/hip_bf16.h>

// Problem constants: B=4, S=2048, D=512, H=8, DK=64
// ws layout (bytes):
//   Xb    @ 0        : 8192*512 bf16        = 8388608
//   Wqkv  @ 8388608  : 1536*512 bf16        = 1572864   (BT: row n = which*512+h*64+dk, col k=d)
//   WoT   @ 9961472  : 512*512 bf16         = 524288    (row n=d, col k=h*64+dk  [permuted concat])
//   Qb    @ 10485760 : 8388608   ([bh][s][dk], PRE-SCALED by log2(e)/8)
//   Kb    @ 18874368 : 8388608   ([bh][s][dk])
//   VTb   @ 27262976 : 8388608   ([bh][dk][s])
//   Oc    @ 35651584 : 8388608   ([b][s][h*64+dk])
// total 44040192 bytes
//
// Session-best configuration (round 14, 92.18 us). Round-15's counted-vmcnt
// pipeline regressed attn 43->48 us and is reverted; the 2-phase full-drain
// loop below is the proven best for all three MFMA kernels.

typedef __bf16 bf16;
typedef __bf16 bf16x8 __attribute__((ext_vector_type(8)));
typedef __bf16 bf16x4 __attribute__((ext_vector_type(4)));
typedef __bf16 bf16x2 __attribute__((ext_vector_type(2)));
typedef float  f32x4  __attribute__((ext_vector_type(4)));
typedef float  f32x16 __attribute__((ext_vector_type(16)));
typedef unsigned int u32;
typedef u32 u32x4 __attribute__((ext_vector_type(4)));

#define AS1 __attribute__((address_space(1)))
#define AS3 __attribute__((address_space(3)))

__device__ __forceinline__ void async_lds16(const void* gsrc, void* ldst) {
  __builtin_amdgcn_global_load_lds((AS1 const void*)gsrc, (AS3 void*)ldst, 16, 0, 0);
}

// single-instruction exp2 (args bounded above by THR=8; very-negative -> 0)
__device__ __forceinline__ float fexp2(float x) {
  float r;
  asm("v_exp_f32 %0, %1" : "=v"(r) : "v"(x));
  return r;
}

// ---------------- fused converter: X->bf16, Wq/Wk/Wv->BT, Wo->WoT ----------------

__global__ __launch_bounds__(256) void k_cvt_all(const float4* __restrict__ X4,
                                                 const float* __restrict__ Wq,
                                                 const float* __restrict__ Wk,
                                                 const float* __restrict__ Wv,
                                                 const float* __restrict__ Wo,
                                                 bf16x4* __restrict__ Xb4,
                                                 bf16* __restrict__ BT,
                                                 bf16* __restrict__ WoT) {
  int t = blockIdx.x * 256 + threadIdx.x;       // < 2097152
  if (t < 1048576) {
    float4 v = X4[t];
    bf16x4 o = { (bf16)v.x, (bf16)v.y, (bf16)v.z, (bf16)v.w };
    Xb4[t] = o;
  } else {
    int u = t - 1048576;                        // < 1048576
    if (u < 786432) {
      int n = u >> 9, d = u & 511;
      int which = n >> 9, h = (n >> 6) & 7, dk = n & 63;
      const float* W = (which == 0) ? Wq : ((which == 1) ? Wk : Wv);
      BT[u] = (bf16)W[((h << 9) + d) * 64 + dk];
    } else {
      int i2 = u - 786432;                      // < 262144
      int d = i2 >> 9, c = i2 & 511;
      int h = c >> 6, dk = c & 63;
      WoT[i2] = (bf16)Wo[(((dk << 3) + h) << 9) + d];
    }
  }
}

// ---------------- GEMM mainloop: 128x128 tile, BK=32, 4 waves, 2-PHASE ----------------
// T3 minimum recipe: double-buffered LDS; STAGE(t+1) at loop top hides L2/L3
// latency under tile-t compute; one vmcnt(0)+barrier per tile.

__device__ __forceinline__ void gemm_tile(const bf16* __restrict__ A,
                                          const bf16* __restrict__ BT,
                                          int K, int m0, int n0,
                                          char* sm, f32x4 acc[4][4]) {
  const int tid = threadIdx.x;
  const int lane = tid & 63, w = tid >> 6;
  const int wm = w >> 1, wn = w & 1;
  const int lr = lane & 15, lg = lane >> 4;
#define GSTAGE(bi, k0) do {                                                        \
    char* base_ = sm + ((bi) << 14);                                               \
    _Pragma("unroll")                                                              \
    for (int i_ = 0; i_ < 2; ++i_) {                                               \
      int off_ = i_ * 256 + tid;                                                   \
      int row_ = off_ >> 2, cb_ = (off_ & 3) << 4;                                 \
      async_lds16((const char*)(A  + (m0 + row_) * K + (k0)) + cb_,                \
                  base_ + off_ * 16);                                              \
      async_lds16((const char*)(BT + (n0 + row_) * K + (k0)) + cb_,                \
                  base_ + 8192 + off_ * 16);                                       \
    }                                                                              \
  } while (0)
  const int NT = K >> 5;
  GSTAGE(0, 0);
  asm volatile("s_waitcnt vmcnt(0)" ::: "memory");
  __builtin_amdgcn_s_barrier();
  __builtin_amdgcn_sched_barrier(0);
  for (int t = 0; t < NT; ++t) {
    char* cb = sm + ((t & 1) << 14);
    if (t + 1 < NT) GSTAGE((t + 1) & 1, (t + 1) << 5);
    bf16x8 af[4], bfr[4];
    #pragma unroll
    for (int u = 0; u < 4; ++u) {
      af[u]  = *(const bf16x8*)(cb +        ((wm * 64 + u * 16 + lr) * 32 + 8 * lg) * 2);
      bfr[u] = *(const bf16x8*)(cb + 8192 + ((wn * 64 + u * 16 + lr) * 32 + 8 * lg) * 2);
    }
    __builtin_amdgcn_s_setprio(1);
    #pragma unroll
    for (int am = 0; am < 4; ++am)
      #pragma unroll
      for (int bn = 0; bn < 4; ++bn)
        acc[am][bn] = __builtin_amdgcn_mfma_f32_16x16x32_bf16(af[am], bfr[bn], acc[am][bn], 0, 0, 0);
    __builtin_amdgcn_s_setprio(0);
    if (t + 1 < NT) {
      asm volatile("s_waitcnt vmcnt(0)" ::: "memory");
      __builtin_amdgcn_s_barrier();
      __builtin_amdgcn_sched_barrier(0);
    }
  }
#undef GSTAGE
}

__global__ __launch_bounds__(256) void k_gemm_qkv(const bf16* __restrict__ A,
                                                  const bf16* __restrict__ BT,
                                                  bf16* __restrict__ Qb,
                                                  bf16* __restrict__ Kb,
                                                  bf16* __restrict__ VTb) {
  __shared__ char sm[32768];
  const int m0 = blockIdx.y * 128, n0 = blockIdx.x * 128;
  f32x4 acc[4][4];
  #pragma unroll
  for (int a = 0; a < 4; ++a)
    #pragma unroll
    for (int b = 0; b < 4; ++b) { f32x4 z = {0.f,0.f,0.f,0.f}; acc[a][b] = z; }
  gemm_tile(A, BT, 512, m0, n0, sm, acc);
  const int lane = threadIdx.x & 63, w = threadIdx.x >> 6;
  const int wm = w >> 1, wn = w & 1, lr = lane & 15, lg = lane >> 4;
  const float qsc = 0.1803368801f;  // log2(e)/sqrt(64), folded into Q
  #pragma unroll
  for (int am = 0; am < 4; ++am)
    #pragma unroll
    for (int bn = 0; bn < 4; ++bn)
      #pragma unroll
      for (int r = 0; r < 4; ++r) {
        int m = m0 + wm * 64 + am * 16 + 4 * lg + r;
        int n = n0 + wn * 64 + bn * 16 + lr;
        int b = m >> 11, s = m & 2047;
        int which = n >> 9, h = (n >> 6) & 7, dk = n & 63;
        int bh = (b << 3) + h;
        float x = acc[am][bn][r];
        if (which == 0)      Qb[((bh << 11) + s) * 64 + dk] = (bf16)(x * qsc);
        else if (which == 1) Kb[((bh << 11) + s) * 64 + dk] = (bf16)x;
        else                 VTb[((bh << 6) + dk) * 2048 + s] = (bf16)x;
      }
}

// output GEMM: 128(M)x64(N) tile, grid 512 = 2 blocks/CU. Same 2-phase loop;
// LDS 2 x (8KB A + 4KB B).
__global__ __launch_bounds__(256) void k_gemm_out(const bf16* __restrict__ A,
                                                  const bf16* __restrict__ BT,
                                                  float* __restrict__ C) {
  __shared__ char sm[24576];
  const int m0 = blockIdx.y * 128, n0 = blockIdx.x * 64;
  const int tid = threadIdx.x;
  const int lane = tid & 63, w = tid >> 6;
  const int wm = w >> 1, wn = w & 1;
  const int lr = lane & 15, lg = lane >> 4;
  f32x4 acc[4][2];
  #pragma unroll
  for (int a = 0; a < 4; ++a)
    #pragma unroll
    for (int b = 0; b < 2; ++b) { f32x4 z = {0.f,0.f,0.f,0.f}; acc[a][b] = z; }
#define GSTAGE2(bi, k0) do {                                                       \
    char* base_ = sm + (bi) * 12288;                                               \
    _Pragma("unroll")                                                              \
    for (int i_ = 0; i_ < 2; ++i_) {                                               \
      int off_ = i_ * 256 + tid;                                                   \
      int row_ = off_ >> 2, cb_ = (off_ & 3) << 4;                                 \
      async_lds16((const char*)(A + (m0 + row_) * 512 + (k0)) + cb_,               \
                  base_ + off_ * 16);                                              \
    }                                                                              \
    {                                                                              \
      int off_ = tid;                                                              \
      int row_ = off_ >> 2, cb_ = (off_ & 3) << 4;                                 \
      async_lds16((const char*)(BT + (n0 + row_) * 512 + (k0)) + cb_,              \
                  base_ + 8192 + off_ * 16);                                       \
    }                                                                              \
  } while (0)
  GSTAGE2(0, 0);
  asm volatile("s_waitcnt vmcnt(0)" ::: "memory");
  __builtin_amdgcn_s_barrier();
  __builtin_amdgcn_sched_barrier(0);
  for (int t = 0; t < 16; ++t) {
    char* cb = sm + (t & 1) * 12288;
    if (t + 1 < 16) GSTAGE2((t + 1) & 1, (t + 1) << 5);
    bf16x8 af[4], bfr[2];
    #pragma unroll
    for (int u = 0; u < 4; ++u)
      af[u] = *(const bf16x8*)(cb + ((wm * 64 + u * 16 + lr) * 32 + 8 * lg) * 2);
    #pragma unroll
    for (int v = 0; v < 2; ++v)
      bfr[v] = *(const bf16x8*)(cb + 8192 + ((wn * 32 + v * 16 + lr) * 32 + 8 * lg) * 2);
    __builtin_amdgcn_s_setprio(1);
    #pragma unroll
    for (int am = 0; am < 4; ++am)
      #pragma unroll
      for (int bn = 0; bn < 2; ++bn)
        acc[am][bn] = __builtin_amdgcn_mfma_f32_16x16x32_bf16(af[am], bfr[bn], acc[am][bn], 0, 0, 0);
    __builtin_amdgcn_s_setprio(0);
    if (t + 1 < 16) {
      asm volatile("s_waitcnt vmcnt(0)" ::: "memory");
      __builtin_amdgcn_s_barrier();
      __builtin_amdgcn_sched_barrier(0);
    }
  }
#undef GSTAGE2
  #pragma unroll
  for (int am = 0; am < 4; ++am)
    #pragma unroll
    for (int bn = 0; bn < 2; ++bn)
      #pragma unroll
      for (int r = 0; r < 4; ++r) {
        int m = m0 + wm * 64 + am * 16 + 4 * lg + r;
        int n = n0 + wn * 32 + bn * 16 + lr;
        C[(m << 9) + n] = acc[am][bn][r];
      }
}

// ---------------- causal flash attention: q-split block, LDS-staged shared K/V ----------------
// (round-11 body — best measured: 42.7 us; r12/r13/r15 alternatives all regressed)
// Block = 4 waves x 32 DIFFERENT q-rows (128 rows) of one (b,h). KVBLK=64.
// K tile + V^T tile double-buffered in LDS (32KB), staged once per block via
// global_load_lds, shared by all 4 waves; stage(t+1) under tile-t compute.
// Swizzle rule #21: linear LDS dest + source-XOR + read-XOR.
// Private per-wave online softmax (no cross-wave combine).

__device__ __forceinline__ void attn_stage(char* base, const bf16* Kh, const bf16* Vh,
                                           int tb, int tid) {
  #pragma unroll
  for (int k = 0; k < 2; ++k) {        // K slots 0..511
    int s = tid + (k << 8);
    int row = s >> 3, g = s & 7;
    async_lds16((const void*)(Kh + ((tb + row) << 6) + ((g ^ (row & 7)) << 3)),
                base + s * 16);
  }
  #pragma unroll
  for (int k = 0; k < 2; ++k) {        // V slots 0..511 (dv-major)
    int s = tid + (k << 8);
    int row = s >> 3, g = s & 7;
    async_lds16((const void*)(Vh + (row << 11) + tb + ((g ^ (row & 7)) << 3)),
                base + 8192 + s * 16);
  }
}

__global__ __launch_bounds__(256, 2) void k_attn6(const bf16* __restrict__ Qb,
                                                  const bf16* __restrict__ Kb,
                                                  const bf16* __restrict__ VTb,
                                                  bf16* __restrict__ Oc) {
  __shared__ char sm[32768];
  const int tid = threadIdx.x, lane = tid & 63, wv = tid >> 6;
  const int l31 = lane & 31, hi = lane >> 5;
  const int bid = blockIdx.x;
  const int bh = bid & 31;
  const int qb = (bid < 256) ? (15 - (bid >> 5)) : ((bid - 256) >> 5);
  const int b = bh >> 3, h = bh & 7;
  const int q0 = qb << 7;
  const int wq0 = q0 + (wv << 5);                // this wave's first q-row
  const bf16* Qh = Qb  + ((size_t)bh << 17);
  const bf16* Kh = Kb  + ((size_t)bh << 17);
  const bf16* Vh = VTb + ((size_t)bh << 17);

  bf16x8 qf[4];
  #pragma unroll
  for (int kd = 0; kd < 4; ++kd)
    qf[kd] = *(const bf16x8*)(Qh + ((wq0 + l31) << 6) + kd * 16 + 8 * hi);

  f32x16 o0, o1;
  #pragma unroll
  for (int r = 0; r < 16; ++r) { o0[r] = 0.f; o1[r] = 0.f; }
  float m_run = -3e38f, lsum = 0.f;

  const int NT = (qb << 1) + 2;                  // tiles cover kv [0, q0+128)
  const int swz = l31 & 7;                       // row&7 for all this lane's reads

  attn_stage(sm, Kh, Vh, 0, tid);

  for (int t = 0; t < NT; ++t) {
    const int tb = t << 6;
    char* cb = sm + ((t & 1) << 14);
    __syncthreads();                             // drains vmcnt: buf[t&1] ready
    if (t + 1 < NT)
      attn_stage(sm + (((t + 1) & 1) << 14), Kh, Vh, (t + 1) << 6, tid);
    if (tb > wq0 + 31) continue;                 // fully above diagonal for this wave

    // QK^T from K LDS: two 32-kv halves
    f32x16 sA, sB;
    #pragma unroll
    for (int r = 0; r < 16; ++r) { sA[r] = 0.f; sB[r] = 0.f; }
    {
      bf16x8 kf[4];
      #pragma unroll
      for (int kd = 0; kd < 4; ++kd)
        kf[kd] = *(const bf16x8*)(cb + l31 * 128 + ((((kd << 1) + hi) ^ swz) << 4));
      __builtin_amdgcn_s_setprio(1);
      #pragma unroll
      for (int kd = 0; kd < 4; ++kd)
        sA = __builtin_amdgcn_mfma_f32_32x32x16_bf16(kf[kd], qf[kd], sA, 0, 0, 0);
      __builtin_amdgcn_s_setprio(0);
      #pragma unroll
      for (int kd = 0; kd < 4; ++kd)
        kf[kd] = *(const bf16x8*)(cb + (32 + l31) * 128 + ((((kd << 1) + hi) ^ swz) << 4));
      __builtin_amdgcn_s_setprio(1);
      #pragma unroll
      for (int kd = 0; kd < 4; ++kd)
        sB = __builtin_amdgcn_mfma_f32_32x32x16_bf16(kf[kd], qf[kd], sB, 0, 0, 0);
      __builtin_amdgcn_s_setprio(0);
    }

    const int sg = wq0 + l31;
    // causal mask (only tiles overlapping the diagonal band)
    if (tb + 63 > wq0) {
      #pragma unroll
      for (int r = 0; r < 16; ++r) {
        int rk = tb + (r & 3) + 8 * (r >> 2) + 4 * hi;
        sA[r] = (rk > sg)      ? -1e30f : sA[r];
        sB[r] = (rk + 32 > sg) ? -1e30f : sB[r];
      }
    }
    // row max: tree + one cross-half exchange
    float tv[16];
    #pragma unroll
    for (int r = 0; r < 16; ++r) tv[r] = fmaxf(sA[r], sB[r]);
    float m0_ = fmaxf(tv[0], tv[1]),  m1_ = fmaxf(tv[2], tv[3]);
    float m2_ = fmaxf(tv[4], tv[5]),  m3_ = fmaxf(tv[6], tv[7]);
    float m4_ = fmaxf(tv[8], tv[9]),  m5_ = fmaxf(tv[10], tv[11]);
    float m6_ = fmaxf(tv[12], tv[13]), m7_ = fmaxf(tv[14], tv[15]);
    float tmax = fmaxf(fmaxf(fmaxf(m0_, m1_), fmaxf(m2_, m3_)),
                       fmaxf(fmaxf(m4_, m5_), fmaxf(m6_, m7_)));
    float tms = fmaxf(tmax, __shfl_xor(tmax, 32));
    // defer-max rescale (T13, THR=8 in exp2 domain)
    if (!__all(tms <= m_run + 8.f)) {
      float mn = fmaxf(m_run, tms);
      float fac = fexp2(m_run - mn);
      #pragma unroll
      for (int r = 0; r < 16; ++r) { o0[r] *= fac; o1[r] *= fac; }
      lsum *= fac;
      m_run = mn;
    }
    // P = exp2(s - m) in place
    #pragma unroll
    for (int r = 0; r < 16; ++r) sA[r] = fexp2(sA[r] - m_run);
    #pragma unroll
    for (int r = 0; r < 16; ++r) sB[r] = fexp2(sB[r] - m_run);
    // row sum
    float a0 = (sA[0]+sB[0]) + (sA[1]+sB[1]),   a1 = (sA[2]+sB[2]) + (sA[3]+sB[3]);
    float a2 = (sA[4]+sB[4]) + (sA[5]+sB[5]),   a3 = (sA[6]+sB[6]) + (sA[7]+sB[7]);
    float a4 = (sA[8]+sB[8]) + (sA[9]+sB[9]),   a5 = (sA[10]+sB[10]) + (sA[11]+sB[11]);
    float a6 = (sA[12]+sB[12]) + (sA[13]+sB[13]), a7 = (sA[14]+sB[14]) + (sA[15]+sB[15]);
    float rs = ((a0 + a1) + (a2 + a3)) + ((a4 + a5) + (a6 + a7));
    lsum += rs + __shfl_xor(rs, 32);

    // per 32-kv half: pack P, permlane -> B-frags; PV from V LDS
    #pragma unroll
    for (int j = 0; j < 2; ++j) {
      u32 pk_[8];
      #pragma unroll
      for (int i = 0; i < 8; ++i) {
        float plo = j ? sB[2 * i] : sA[2 * i];
        float phi = j ? sB[2 * i + 1] : sA[2 * i + 1];
        bf16x2 pr = { (bf16)plo, (bf16)phi };
        pk_[i] = __builtin_bit_cast(u32, pr);
      }
      asm volatile("v_permlane32_swap_b32 %0, %1" : "+v"(pk_[0]), "+v"(pk_[2]));
      asm volatile("v_permlane32_swap_b32 %0, %1" : "+v"(pk_[1]), "+v"(pk_[3]));
      asm volatile("v_permlane32_swap_b32 %0, %1" : "+v"(pk_[4]), "+v"(pk_[6]));
      asm volatile("v_permlane32_swap_b32 %0, %1" : "+v"(pk_[5]), "+v"(pk_[7]));
      u32x4 w0 = { pk_[0], pk_[1], pk_[2], pk_[3] };
      u32x4 w1 = { pk_[4], pk_[5], pk_[6], pk_[7] };
      bf16x8 pb0 = __builtin_bit_cast(bf16x8, w0);
      bf16x8 pb1 = __builtin_bit_cast(bf16x8, w1);
      // V^T A-frags from LDS: dv = dvt*32+l31, 16B-group gg = j*4 + ks*2 + hi
      const char* vb = cb + 8192;
      bf16x8 v00 = *(const bf16x8*)(vb + l31 * 128        + ((((j << 2) + hi) ^ swz) << 4));
      bf16x8 v01 = *(const bf16x8*)(vb + l31 * 128        + ((((j << 2) + 2 + hi) ^ swz) << 4));
      bf16x8 v10 = *(const bf16x8*)(vb + (32 + l31) * 128 + ((((j << 2) + hi) ^ swz) << 4));
      bf16x8 v11 = *(const bf16x8*)(vb + (32 + l31) * 128 + ((((j << 2) + 2 + hi) ^ swz) << 4));
      __builtin_amdgcn_s_setprio(1);
      o0 = __builtin_amdgcn_mfma_f32_32x32x16_bf16(v00, pb0, o0, 0, 0, 0);
      o0 = __builtin_amdgcn_mfma_f32_32x32x16_bf16(v01, pb1, o0, 0, 0, 0);
      o1 = __builtin_amdgcn_mfma_f32_32x32x16_bf16(v10, pb0, o1, 0, 0, 0);
      o1 = __builtin_amdgcn_mfma_f32_32x32x16_bf16(v11, pb1, o1, 0, 0, 0);
      __builtin_amdgcn_s_setprio(0);
    }
  }

  // epilogue: per-wave normalize and coalesced write (no cross-wave combine)
  float rn = 1.f / lsum;
  const int sg = wq0 + l31;
  bf16* Orow = Oc + (((size_t)((b << 11) + sg)) << 9) + (h << 6);
  #pragma unroll
  for (int g = 0; g < 4; ++g) {
    bf16x4 v0, v1;
    #pragma unroll
    for (int i = 0; i < 4; ++i) {
      v0[i] = (bf16)(o0[4 * g + i] * rn);
      v1[i] = (bf16)(o1[4 * g + i] * rn);
    }
    *(bf16x4*)(Orow + 4 * hi + 8 * g)      = v0;
    *(bf16x4*)(Orow + 32 + 4 * hi + 8 * g) = v1;
  }
}

// ---------------- launch ----------------

extern "C" void kernel_launch(void* const* d_in, const int* in_sizes, int n_in,
                              void* d_out, int out_size, void* d_ws, size_t ws_size,
                              hipStream_t stream) {
  (void)in_sizes; (void)n_in; (void)out_size; (void)ws_size;
  const float* X  = (const float*)d_in[0];
  const float* Wq = (const float*)d_in[1];
  const float* Wk = (const float*)d_in[2];
  const float* Wv = (const float*)d_in[3];
  const float* Wo = (const float*)d_in[4];
  float* out = (float*)d_out;
  char* ws = (char*)d_ws;
  bf16* Xb   = (bf16*)(ws);
  bf16* Wqkv = (bf16*)(ws + 8388608);
  bf16* WoT  = (bf16*)(ws + 9961472);
  bf16* Qb   = (bf16*)(ws + 10485760);
  bf16* Kb   = (bf16*)(ws + 18874368);
  bf16* VTb  = (bf16*)(ws + 27262976);
  bf16* Oc   = (bf16*)(ws + 35651584);

  k_cvt_all<<<8192, 256, 0, stream>>>((const float4*)X, Wq, Wk, Wv, Wo,
                                      (bf16x4*)Xb, Wqkv, WoT);
  k_gemm_qkv<<<dim3(12, 64), 256, 0, stream>>>(Xb, Wqkv, Qb, Kb, VTb);
  k_attn6<<<512, 256, 0, stream>>>(Qb, Kb, VTb, Oc);
  k_gemm_out<<<dim3(8, 64), 256, 0, stream>>>(Oc, WoT, out);
}